// Round 7
// baseline (133.725 us; speedup 1.0000x reference)
//
#include <hip/hip_runtime.h>
#include <hip/hip_bf16.h>

#define SEQ 8192
#define HD 128
#define BM 256
#define BN 64
#define NQT (SEQ / BM)   // 32
#define THREADS 512

typedef __bf16 bf16_t;
typedef __bf16 bf16x2 __attribute__((ext_vector_type(2)));
typedef __bf16 bf16x8 __attribute__((ext_vector_type(8)));
typedef float f32x4 __attribute__((ext_vector_type(4)));
typedef float f32x16 __attribute__((ext_vector_type(16)));
typedef unsigned int u32x4 __attribute__((ext_vector_type(4)));

#if __has_builtin(__builtin_amdgcn_exp2f)
__device__ inline float exp2_fast(float x) { return __builtin_amdgcn_exp2f(x); }
#else
__device__ inline float exp2_fast(float x) { return exp2f(x); }
#endif

// async global->LDS DMA, 16 B per lane; lds dest wave-uniform, HW adds lane*16
__device__ inline void load_lds16(const void* g, void* l) {
  __builtin_amdgcn_global_load_lds(
      (const __attribute__((address_space(1))) void*)g,
      (__attribute__((address_space(3))) void*)l, 16, 0, 0);
}

// ---------------- prep ----------------
// Kb blocked: [tile T][d-chunk c 0..15][key r 0..63][8]  = K[T*64+r][c*8+j]
// VT blocked: [tile T][key-chunk kc 0..7][d 0..127][8]   = V[T*64+kc*8+j][d]
__global__ __launch_bounds__(256) void prep_kernel(const float* __restrict__ K,
                                                   const float* __restrict__ V,
                                                   bf16_t* __restrict__ Kb,
                                                   bf16_t* __restrict__ VT) {
  const int b = (int)blockIdx.x;
  const int tid = (int)threadIdx.x;
  if (b < 256) {
    __shared__ float tile[64][65];
    const int T = b & 127;
    const int d0 = (b >> 7) * 64;
    const int s0 = T * 64;
    const int r = tid >> 2;
    const int c0 = (tid & 3) * 16;
#pragma unroll
    for (int j4 = 0; j4 < 4; ++j4) {
      float4 x = *(const float4*)&V[(size_t)(s0 + r) * HD + d0 + c0 + j4 * 4];
      tile[r][c0 + j4 * 4 + 0] = x.x;
      tile[r][c0 + j4 * 4 + 1] = x.y;
      tile[r][c0 + j4 * 4 + 2] = x.z;
      tile[r][c0 + j4 * 4 + 3] = x.w;
    }
    __syncthreads();
    const int d_l = tid & 63;
    const int kc0 = (tid >> 6) * 2;
#pragma unroll
    for (int k2 = 0; k2 < 2; ++k2) {
      const int kc = kc0 + k2;
      bf16x8 wv;
#pragma unroll
      for (int j = 0; j < 8; ++j) wv[j] = (bf16_t)tile[kc * 8 + j][d_l];
      *(bf16x8*)&VT[((size_t)(T * 8 + kc) * 128 + d0 + d_l) * 8] = wv;
    }
  } else {
    const int base = (b - 256) * 2048 + tid * 8;
    const int row = base >> 7;
    const int c = (base >> 3) & 15;
    const int T = row >> 6;
    const int r = row & 63;
    float4 a = *(const float4*)&K[base];
    float4 cc = *(const float4*)&K[base + 4];
    bf16x8 f;
    f[0] = (bf16_t)a.x; f[1] = (bf16_t)a.y; f[2] = (bf16_t)a.z; f[3] = (bf16_t)a.w;
    f[4] = (bf16_t)cc.x; f[5] = (bf16_t)cc.y; f[6] = (bf16_t)cc.z; f[7] = (bf16_t)cc.w;
    *(bf16x8*)&Kb[((size_t)(T * 16 + c) * 64 + r) * 8] = f;
  }
}

// ---------------- main flash-attention kernel ----------------
// BM=256; 8 waves: qp = w&3 owns q-tiles {2qp, 2qp+1} (32 rows each), g = w>>2
// = key-half for QK and d-half for PV. Every LDS b128 read feeds 2 MFMAs.
// Mid-iter barrier is lgkm-only (DMA stays in flight); end barrier drains DMA.
__global__ __launch_bounds__(THREADS, 2) void fattn_kernel(
    const float* __restrict__ Q, const bf16_t* __restrict__ Kb,
    const bf16_t* __restrict__ VT, float* __restrict__ Opart,
    float* __restrict__ Lpart, int kshift, int nit) {
  __shared__ __align__(16) bf16_t kt2[2][16][64][8];   // 32 KB [buf][d-chunk][key][8]
  __shared__ __align__(16) bf16_t vt2[2][8][128][8];   // 32 KB [buf][key-chunk][d][8]
  __shared__ __align__(16) char pbuf[8][4][64][16];    // 32 KB [q-tile][C][lane][16B]

  const int tid = (int)threadIdx.x;
  const int lane = tid & 63;
  const int w = tid >> 6;
  const int qp = w & 3;
  const int g = w >> 2;
  const int h = lane >> 5;
  const int n32 = lane & 31;

  const int qt = (int)blockIdx.x >> kshift;
  const int sp = (int)blockIdx.x & ((1 << kshift) - 1);
  const int qbase = qt * BM;
  const int tile0 = sp * nit;

  const float SC2 = 0.08838834764831845f * 1.4426950408889634f; // (1/sqrt(128))*log2e

  // Q B-frags for both q-tiles (n = n32, k-dim = d), pre-scaled
  bf16x8 qf[2][8];
#pragma unroll
  for (int t = 0; t < 2; ++t) {
    const float* qp_ = Q + (size_t)(qbase + (qp * 2 + t) * 32 + n32) * HD + h * 8;
#pragma unroll
    for (int kk = 0; kk < 8; ++kk) {
      float4 a = *(const float4*)(qp_ + kk * 16);
      float4 b = *(const float4*)(qp_ + kk * 16 + 4);
      bf16x8 f;
      f[0] = (bf16_t)(a.x * SC2); f[1] = (bf16_t)(a.y * SC2);
      f[2] = (bf16_t)(a.z * SC2); f[3] = (bf16_t)(a.w * SC2);
      f[4] = (bf16_t)(b.x * SC2); f[5] = (bf16_t)(b.y * SC2);
      f[6] = (bf16_t)(b.z * SC2); f[7] = (bf16_t)(b.w * SC2);
      qf[t][kk] = f;
    }
  }

  f32x16 o_acc[2][2];
#pragma unroll
  for (int t = 0; t < 2; ++t)
#pragma unroll
    for (int ot = 0; ot < 2; ++ot)
#pragma unroll
      for (int e = 0; e < 16; ++e) o_acc[t][ot][e] = 0.f;
  float l_acc[2] = {0.f, 0.f};

  // per-lane LDS bases (element offsets within a buffer; buffer toggle = ^8192)
  const bf16_t* ktb = &kt2[0][h][g * 32 + n32][0];          // + kk*1024 el
  const bf16_t* vtb = &vt2[0][h][g * 64 + n32][0];          // + C*2048 + ot*256 el
  char* pw[2];
  const char* pr[2];
#pragma unroll
  for (int t = 0; t < 2; ++t) {
    pw[t] = &pbuf[qp * 2 + t][g * 2][lane][0];              // + kk2*1024 B
    pr[t] = &pbuf[qp * 2 + t][0][h * 32 + n32][0];          // + C*1024 B
  }

  // DMA pointers: regions rr = 2w, 2w+1 (1 KB each); tile stride 8192 elements
  const bf16_t* ksrc[2];
  const bf16_t* vsrc[2];
  char* kdst[2];
  char* vdst[2];
#pragma unroll
  for (int t = 0; t < 2; ++t) {
    const int rr = w * 2 + t;
    ksrc[t] = Kb + ((size_t)(tile0 * 16 + rr) * 64 + lane) * 8;
    vsrc[t] = VT + ((size_t)(tile0 * 8 + (rr >> 1)) * 128 + (rr & 1) * 64 + lane) * 8;
    kdst[t] = (char*)&kt2[0][0][0][0] + rr * 1024;
    vdst[t] = (char*)&vt2[0][0][0][0] + rr * 1024;
  }

  // preload tile0 -> buffer 0
#pragma unroll
  for (int t = 0; t < 2; ++t) {
    load_lds16(ksrc[t], kdst[t]);
    load_lds16(vsrc[t], vdst[t]);
    ksrc[t] += 8192;
    vsrc[t] += 8192;
  }
  __syncthreads();

  int bo = 0;        // element toggle for reads
  int nb = 16384;    // byte toggle for DMA dest

  for (int it = 0; it < nit; ++it) {
    if (it + 1 < nit) {
#pragma unroll
      for (int t = 0; t < 2; ++t) {
        load_lds16(ksrc[t], kdst[t] + nb);
        load_lds16(vsrc[t], vdst[t] + nb);
        ksrc[t] += 8192;
        vsrc[t] += 8192;
      }
    }

    // ---- S^T(key-half g) = K_g Q^T for both q-tiles ----
    const bf16_t* kc_ = ktb + bo;
    f32x16 sacc[2];
#pragma unroll
    for (int t = 0; t < 2; ++t)
#pragma unroll
      for (int e = 0; e < 16; ++e) sacc[t][e] = 0.f;
#pragma unroll
    for (int kk = 0; kk < 8; ++kk) {
      bf16x8 af = *(const bf16x8*)(kc_ + kk * 1024);
      sacc[0] = __builtin_amdgcn_mfma_f32_32x32x16_bf16(af, qf[0][kk], sacc[0], 0, 0, 0);
      sacc[1] = __builtin_amdgcn_mfma_f32_32x32x16_bf16(af, qf[1][kk], sacc[1], 0, 0, 0);
    }

    // ---- exp -> pack -> half-wave exchange -> A-layout P chunks to LDS ----
#pragma unroll
    for (int t = 0; t < 2; ++t) {
#pragma unroll
      for (int kk2 = 0; kk2 < 2; ++kk2) {
        float pf[8];
#pragma unroll
        for (int j = 0; j < 8; ++j) pf[j] = exp2_fast(sacc[t][8 * kk2 + j]);
#pragma unroll
        for (int j = 0; j < 8; ++j) l_acc[t] += pf[j];
        bf16x2 p0, p1, p2, p3;
        p0[0] = (bf16_t)pf[0]; p0[1] = (bf16_t)pf[1];
        p1[0] = (bf16_t)pf[2]; p1[1] = (bf16_t)pf[3];
        p2[0] = (bf16_t)pf[4]; p2[1] = (bf16_t)pf[5];
        p3[0] = (bf16_t)pf[6]; p3[1] = (bf16_t)pf[7];
        const unsigned int sA = __builtin_bit_cast(unsigned int, p0);
        const unsigned int sB = __builtin_bit_cast(unsigned int, p1);
        const unsigned int sC = __builtin_bit_cast(unsigned int, p2);
        const unsigned int sD = __builtin_bit_cast(unsigned int, p3);
        unsigned int s0 = h ? sA : sC, s1 = h ? sB : sD;
        unsigned int r0 = __shfl_xor(s0, 32);
        unsigned int r1 = __shfl_xor(s1, 32);
        unsigned int o0 = h ? sC : sA, o1 = h ? sD : sB;
        u32x4 fv;
        fv[0] = h ? r0 : o0; fv[1] = h ? r1 : o1;
        fv[2] = h ? o0 : r0; fv[3] = h ? o1 : r1;
        *(u32x4*)(pw[t] + kk2 * 1024) = fv;
      }
    }

    // LDS-visibility barrier only (DMA stays in flight: no vmcnt drain)
    asm volatile("s_waitcnt lgkmcnt(0)\n\ts_barrier" ::: "memory");

    // ---- O(d-half g) += P(all 64 keys) V, both q-tiles ----
    const bf16_t* vc_ = vtb + bo;
#pragma unroll
    for (int C = 0; C < 4; ++C) {
      bf16x8 pa0 = *(const bf16x8*)(pr[0] + C * 1024);
      bf16x8 pa1 = *(const bf16x8*)(pr[1] + C * 1024);
#pragma unroll
      for (int ot = 0; ot < 2; ++ot) {
        bf16x8 vb = *(const bf16x8*)(vc_ + C * 2048 + ot * 256);
        o_acc[0][ot] = __builtin_amdgcn_mfma_f32_32x32x16_bf16(pa0, vb, o_acc[0][ot], 0, 0, 0);
        o_acc[1][ot] = __builtin_amdgcn_mfma_f32_32x32x16_bf16(pa1, vb, o_acc[1][ot], 0, 0, 0);
      }
    }

    __syncthreads();   // drains this iter's DMA + LDS reads; buffer swap
    bo ^= 8192;
    nb ^= 16384;
  }

  // ---- epilogue: each wave owns a distinct q x d block of Opart ----
#pragma unroll
  for (int t = 0; t < 2; ++t) {
    float* op = Opart + ((size_t)sp * SEQ + qbase + (qp * 2 + t) * 32) * HD + g * 64;
#pragma unroll
    for (int ot = 0; ot < 2; ++ot)
#pragma unroll
      for (int reg = 0; reg < 16; ++reg) {
        const int row = (reg & 3) + 8 * (reg >> 2) + 4 * h;
        op[row * HD + ot * 32 + n32] = o_acc[t][ot][reg];
      }
  }
  // l: sum halves within wave, then cross-g via LDS (pbuf is dead)
  float l0 = l_acc[0] + __shfl_xor(l_acc[0], 32);
  float l1 = l_acc[1] + __shfl_xor(l_acc[1], 32);
  float* lfb = (float*)pbuf;
  if (lane < 32) {
    lfb[g * 256 + (qp * 2 + 0) * 32 + n32] = l0;
    lfb[g * 256 + (qp * 2 + 1) * 32 + n32] = l1;
  }
  __syncthreads();
  if (g == 0 && lane < 32) {
    Lpart[(size_t)sp * SEQ + qbase + (qp * 2 + 0) * 32 + n32] =
        l0 + lfb[256 + (qp * 2 + 0) * 32 + n32];
    Lpart[(size_t)sp * SEQ + qbase + (qp * 2 + 1) * 32 + n32] =
        l1 + lfb[256 + (qp * 2 + 1) * 32 + n32];
  }
}

// ---------------- combine: out = sum_s O_s / sum_s l_s ----------------
__global__ __launch_bounds__(256) void combine_kernel(const float* __restrict__ Opart,
                                                      const float* __restrict__ Lpart,
                                                      float* __restrict__ out, int ksplit) {
  const int tid = (int)threadIdx.x;
  const int row = (int)blockIdx.x * 8 + (tid >> 5);
  const int c0 = (tid & 31) * 4;
  float lsum = 0.f;
  for (int s = 0; s < ksplit; ++s) lsum += Lpart[(size_t)s * SEQ + row];
  f32x4 acc;
#pragma unroll
  for (int e = 0; e < 4; ++e) acc[e] = 0.f;
  for (int s = 0; s < ksplit; ++s) {
    f32x4 o = *(const f32x4*)&Opart[((size_t)s * SEQ + row) * HD + c0];
#pragma unroll
    for (int e = 0; e < 4; ++e) acc[e] += o[e];
  }
  const float inv = 1.0f / lsum;
  f32x4 res;
#pragma unroll
  for (int e = 0; e < 4; ++e) res[e] = acc[e] * inv;
  *(f32x4*)&out[(size_t)row * HD + c0] = res;
}

extern "C" void kernel_launch(void* const* d_in, const int* in_sizes, int n_in,
                              void* d_out, int out_size, void* d_ws, size_t ws_size,
                              hipStream_t stream) {
  const float* Q = (const float*)d_in[0];
  const float* K = (const float*)d_in[1];
  const float* V = (const float*)d_in[2];
  float* out = (float*)d_out;

  int ksplit = 16, kshift = 4;
  while (ksplit > 1) {
    size_t need = (size_t)ksplit * SEQ * HD * 4
                + (size_t)ksplit * SEQ * 4
                + (size_t)SEQ * HD * 2 * 2;
    if (need <= ws_size) break;
    ksplit >>= 1; kshift--;
  }

  char* ws = (char*)d_ws;
  float* Opart = (float*)ws;
  float* Lpart = (float*)(ws + (size_t)ksplit * SEQ * HD * 4);
  bf16_t* Kb = (bf16_t*)(ws + (size_t)ksplit * SEQ * HD * 4 + (size_t)ksplit * SEQ * 4);
  bf16_t* VT = Kb + (size_t)SEQ * HD;

  const int nit = SEQ / (ksplit * BN);

  prep_kernel<<<768, 256, 0, stream>>>(K, V, Kb, VT);
  fattn_kernel<<<NQT * ksplit, THREADS, 0, stream>>>(Q, Kb, VT, Opart, Lpart, kshift, nit);
  combine_kernel<<<SEQ / 8, 256, 0, stream>>>(Opart, Lpart, out, ksplit);
}

// Round 8
// 123.085 us; speedup vs baseline: 1.0864x; 1.0864x over previous
//
#include <hip/hip_runtime.h>
#include <hip/hip_bf16.h>

#define SEQ 8192
#define HD 128
#define BM 128
#define BN 64
#define NQT (SEQ / BM)   // 64
#define THREADS 512

typedef __bf16 bf16_t;
typedef __bf16 bf16x2 __attribute__((ext_vector_type(2)));
typedef __bf16 bf16x8 __attribute__((ext_vector_type(8)));
typedef float f32x4 __attribute__((ext_vector_type(4)));
typedef float f32x16 __attribute__((ext_vector_type(16)));
typedef unsigned int u32x4 __attribute__((ext_vector_type(4)));

#if __has_builtin(__builtin_amdgcn_exp2f)
__device__ inline float exp2_fast(float x) { return __builtin_amdgcn_exp2f(x); }
#else
__device__ inline float exp2_fast(float x) { return exp2f(x); }
#endif

// async global->LDS DMA, 16 B per lane; lds dest wave-uniform, HW adds lane*16
__device__ inline void load_lds16(const void* g, void* l) {
  __builtin_amdgcn_global_load_lds(
      (const __attribute__((address_space(1))) void*)g,
      (__attribute__((address_space(3))) void*)l, 16, 0, 0);
}

// ---------------- prep ----------------
// Kb blocked: [tile T][d-chunk c 0..15][key r 0..63][8]  = K[T*64+r][c*8+j]
// VT blocked: [tile T][key-chunk kc 0..7][d 0..127][8]   = V[T*64+kc*8+j][d]
__global__ __launch_bounds__(256) void prep_kernel(const float* __restrict__ K,
                                                   const float* __restrict__ V,
                                                   bf16_t* __restrict__ Kb,
                                                   bf16_t* __restrict__ VT) {
  const int b = (int)blockIdx.x;
  const int tid = (int)threadIdx.x;
  if (b < 256) {
    __shared__ float tile[64][65];
    const int T = b & 127;
    const int d0 = (b >> 7) * 64;
    const int s0 = T * 64;
    const int r = tid >> 2;
    const int c0 = (tid & 3) * 16;
#pragma unroll
    for (int j4 = 0; j4 < 4; ++j4) {
      float4 x = *(const float4*)&V[(size_t)(s0 + r) * HD + d0 + c0 + j4 * 4];
      tile[r][c0 + j4 * 4 + 0] = x.x;
      tile[r][c0 + j4 * 4 + 1] = x.y;
      tile[r][c0 + j4 * 4 + 2] = x.z;
      tile[r][c0 + j4 * 4 + 3] = x.w;
    }
    __syncthreads();
    const int d_l = tid & 63;
    const int kc0 = (tid >> 6) * 2;
#pragma unroll
    for (int k2 = 0; k2 < 2; ++k2) {
      const int kc = kc0 + k2;
      bf16x8 wv;
#pragma unroll
      for (int j = 0; j < 8; ++j) wv[j] = (bf16_t)tile[kc * 8 + j][d_l];
      *(bf16x8*)&VT[((size_t)(T * 8 + kc) * 128 + d0 + d_l) * 8] = wv;
    }
  } else {
    const int base = (b - 256) * 2048 + tid * 8;
    const int row = base >> 7;
    const int c = (base >> 3) & 15;
    const int T = row >> 6;
    const int r = row & 63;
    float4 a = *(const float4*)&K[base];
    float4 cc = *(const float4*)&K[base + 4];
    bf16x8 f;
    f[0] = (bf16_t)a.x; f[1] = (bf16_t)a.y; f[2] = (bf16_t)a.z; f[3] = (bf16_t)a.w;
    f[4] = (bf16_t)cc.x; f[5] = (bf16_t)cc.y; f[6] = (bf16_t)cc.z; f[7] = (bf16_t)cc.w;
    *(bf16x8*)&Kb[((size_t)(T * 16 + c) * 64 + r) * 8] = f;
  }
}

// ---------------- main flash-attention kernel ----------------
// 8 waves: qw = w&3 (32 q-rows), g = w>>2 (key-half for QK, d-half for PV).
// QK: S^T = K_g Q^T (C/D col = q). exp'd P kept as MFMA B-frags: own 2 chunks
// in registers, sibling's 2 via pbuf. PV computes O^T = V^T P (A = V^T from
// LDS, B = P) -> o_acc 32 regs. Mid barrier is lgkm-only (DMA in flight);
// end __syncthreads drains DMA after a full iteration of cover.
__global__ __launch_bounds__(THREADS, 4) void fattn_kernel(
    const float* __restrict__ Q, const bf16_t* __restrict__ Kb,
    const bf16_t* __restrict__ VT, float* __restrict__ OpartT,
    float* __restrict__ Lpart, int kshift, int nit) {
  __shared__ __align__(16) bf16_t kt2[2][16][64][8];  // 32 KB [buf][d-chunk][key][8]
  __shared__ __align__(16) bf16_t vt2[2][8][128][8];  // 32 KB [buf][key-chunk][d][8]
  __shared__ __align__(16) char pbuf[4][4][64][16];   // 16 KB [qw][key-chunk16][lane][16B]

  const int tid = (int)threadIdx.x;
  const int lane = tid & 63;
  const int w = tid >> 6;
  const int qw = w & 3;
  const int g = w >> 2;
  const int h = lane >> 5;
  const int n32 = lane & 31;

  const int qt = (int)blockIdx.x >> kshift;
  const int sp = (int)blockIdx.x & ((1 << kshift) - 1);
  const int qbase = qt * BM;
  const int tile0 = sp * nit;

  const float SC2 = 0.08838834764831845f * 1.4426950408889634f; // (1/sqrt(128))*log2e

  // Q B-frags (n = n32 = q-row, k-dim = d), pre-scaled
  bf16x8 qf[8];
  {
    const float* qp = Q + (size_t)(qbase + qw * 32 + n32) * HD + h * 8;
#pragma unroll
    for (int kk = 0; kk < 8; ++kk) {
      float4 a = *(const float4*)(qp + kk * 16);
      float4 b = *(const float4*)(qp + kk * 16 + 4);
      bf16x8 f;
      f[0] = (bf16_t)(a.x * SC2); f[1] = (bf16_t)(a.y * SC2);
      f[2] = (bf16_t)(a.z * SC2); f[3] = (bf16_t)(a.w * SC2);
      f[4] = (bf16_t)(b.x * SC2); f[5] = (bf16_t)(b.y * SC2);
      f[6] = (bf16_t)(b.z * SC2); f[7] = (bf16_t)(b.w * SC2);
      qf[kk] = f;
    }
  }

  f32x16 o_acc[2];
#pragma unroll
  for (int i = 0; i < 2; ++i)
#pragma unroll
    for (int e = 0; e < 16; ++e) o_acc[i][e] = 0.f;
  float l_acc = 0.f;

  // DMA pointers: regions rr = 2w, 2w+1 (1 KB each); tile stride 8192 elements
  const bf16_t* ksrc[2];
  const bf16_t* vsrc[2];
  char* kdst[2];
  char* vdst[2];
#pragma unroll
  for (int t = 0; t < 2; ++t) {
    const int rr = w * 2 + t;
    ksrc[t] = Kb + ((size_t)(tile0 * 16 + rr) * 64 + lane) * 8;
    vsrc[t] = VT + ((size_t)(tile0 * 8 + (rr >> 1)) * 128 + (rr & 1) * 64 + lane) * 8;
    kdst[t] = (char*)&kt2[0][0][0][0] + rr * 1024;
    vdst[t] = (char*)&vt2[0][0][0][0] + rr * 1024;
  }

  // preload tile0 -> buffer 0
#pragma unroll
  for (int t = 0; t < 2; ++t) {
    load_lds16(ksrc[t], kdst[t]);
    load_lds16(vsrc[t], vdst[t]);
    ksrc[t] += 8192;
    vsrc[t] += 8192;
  }
  __syncthreads();

  // per-lane LDS read bases (element offsets; buffer toggle bo ^= 8192)
  const bf16_t* ktb = &kt2[0][h][g * 32 + n32][0];         // + kk*1024
  const bf16_t* vtbA = &vt2[0][h][g * 64 + n32][0];        // + c*2048 + dt*256
  int bo = 0;
  int nb = 16384;

  for (int it = 0; it < nit; ++it) {
    if (it + 1 < nit) {
#pragma unroll
      for (int t = 0; t < 2; ++t) {
        load_lds16(ksrc[t], kdst[t] + nb);
        load_lds16(vsrc[t], vdst[t] + nb);
        ksrc[t] += 8192;
        vsrc[t] += 8192;
      }
    }

    // ---- S^T(key-half g) = K_g Q^T : 32 x 32, K-dim 128 ----
    const bf16_t* kc_ = ktb + bo;
    f32x16 sacc;
#pragma unroll
    for (int e = 0; e < 16; ++e) sacc[e] = 0.f;
#pragma unroll
    for (int kk = 0; kk < 8; ++kk) {
      bf16x8 af = *(const bf16x8*)(kc_ + kk * 1024);
      sacc = __builtin_amdgcn_mfma_f32_32x32x16_bf16(af, qf[kk], sacc, 0, 0, 0);
    }

    // ---- exp -> pack -> half-wave exchange -> P B-frags (keep own in regs,
    //      publish to pbuf for the sibling key-half wave) ----
    // sacc[r] = S^T[key = g*32 + (r&3)+8*(r>>2)+4h][q = n32]
    bf16x8 pown[2];
#pragma unroll
    for (int kk2 = 0; kk2 < 2; ++kk2) {
      float pf[8];
#pragma unroll
      for (int j = 0; j < 8; ++j) pf[j] = exp2_fast(sacc[8 * kk2 + j]);
#pragma unroll
      for (int j = 0; j < 8; ++j) l_acc += pf[j];
      bf16x2 p0, p1, p2, p3;
      p0[0] = (bf16_t)pf[0]; p0[1] = (bf16_t)pf[1];
      p1[0] = (bf16_t)pf[2]; p1[1] = (bf16_t)pf[3];
      p2[0] = (bf16_t)pf[4]; p2[1] = (bf16_t)pf[5];
      p3[0] = (bf16_t)pf[6]; p3[1] = (bf16_t)pf[7];
      const unsigned int sA = __builtin_bit_cast(unsigned int, p0);
      const unsigned int sB = __builtin_bit_cast(unsigned int, p1);
      const unsigned int sC = __builtin_bit_cast(unsigned int, p2);
      const unsigned int sD = __builtin_bit_cast(unsigned int, p3);
      unsigned int s0 = h ? sA : sC, s1 = h ? sB : sD;
      unsigned int r0 = __shfl_xor(s0, 32);
      unsigned int r1 = __shfl_xor(s1, 32);
      unsigned int o0 = h ? sC : sA, o1 = h ? sD : sB;
      u32x4 fv;
      fv[0] = h ? r0 : o0; fv[1] = h ? r1 : o1;
      fv[2] = h ? o0 : r0; fv[3] = h ? o1 : r1;
      pown[kk2] = __builtin_bit_cast(bf16x8, fv);
      *(u32x4*)&pbuf[qw][g * 2 + kk2][lane][0] = fv;
    }

    // LDS-visibility barrier only (DMA stays in flight: no vmcnt drain)
    asm volatile("s_waitcnt lgkmcnt(0)\n\ts_barrier" ::: "memory");

    // ---- O^T(d-half g) += V^T P over all 64 keys ----
    const bf16_t* vc_ = vtbA + bo;
#pragma unroll
    for (int c = 0; c < 4; ++c) {
      bf16x8 pb = ((c >> 1) == g) ? pown[c & 1]
                                  : *(const bf16x8*)&pbuf[qw][c][lane][0];
#pragma unroll
      for (int dt = 0; dt < 2; ++dt) {
        bf16x8 av = *(const bf16x8*)(vc_ + (2 * c) * 1024 + dt * 256);
        o_acc[dt] = __builtin_amdgcn_mfma_f32_32x32x16_bf16(av, pb, o_acc[dt], 0, 0, 0);
      }
    }

    __syncthreads();   // drains this iter's DMA + LDS reads; buffer swap
    bo ^= 8192;
    nb ^= 16384;
  }

  // ---- epilogue: O^T block store (coalesced along q) + l combine ----
  {
    float* op = OpartT + (size_t)sp * HD * SEQ + qbase + qw * 32 + n32;
#pragma unroll
    for (int dt = 0; dt < 2; ++dt)
#pragma unroll
      for (int reg = 0; reg < 16; ++reg) {
        const int d = g * 64 + dt * 32 + (reg & 3) + 8 * (reg >> 2) + 4 * h;
        op[(size_t)d * SEQ] = o_acc[dt][reg];
      }
    float l = l_acc + __shfl_xor(l_acc, 32);
    float* lfb = (float*)pbuf;
    if (lane < 32) lfb[g * 128 + qw * 32 + n32] = l;
    __syncthreads();
    if (g == 0 && lane < 32)
      Lpart[(size_t)sp * SEQ + qbase + qw * 32 + n32] = l + lfb[128 + qw * 32 + n32];
  }
}

// ---------------- combine: out[q][d] = (sum_s OpartT[s][d][q]) / sum_s l_s[q] ----
__global__ __launch_bounds__(256) void combine_kernel(const float* __restrict__ OpartT,
                                                      const float* __restrict__ Lpart,
                                                      float* __restrict__ out, int ksplit) {
  __shared__ float tile[64][68];
  __shared__ float lbuf[64];
  const int tid = (int)threadIdx.x;
  const int q0 = (int)blockIdx.x * 64;
  if (tid < 64) {
    float s = 0.f;
    for (int sp = 0; sp < ksplit; ++sp) s += Lpart[(size_t)sp * SEQ + q0 + tid];
    lbuf[tid] = 1.0f / s;
  }
  __syncthreads();
  const int dd = tid >> 2, qc = tid & 3;   // phase A mapping
  const int q = tid >> 2, dc = tid & 3;    // phase B mapping
  for (int db = 0; db < 2; ++db) {
    f32x4 acc[4];
#pragma unroll
    for (int jj = 0; jj < 4; ++jj)
#pragma unroll
      for (int e = 0; e < 4; ++e) acc[jj][e] = 0.f;
    for (int sp = 0; sp < ksplit; ++sp) {
      const float* src = OpartT + ((size_t)sp * HD + db * 64 + dd) * SEQ + q0 + qc * 16;
#pragma unroll
      for (int jj = 0; jj < 4; ++jj) {
        f32x4 v = *(const f32x4*)(src + jj * 4);
#pragma unroll
        for (int e = 0; e < 4; ++e) acc[jj][e] += v[e];
      }
    }
#pragma unroll
    for (int jj = 0; jj < 4; ++jj) *(f32x4*)&tile[dd][qc * 16 + jj * 4] = acc[jj];
    __syncthreads();
    const float inv = lbuf[q];
#pragma unroll
    for (int jj = 0; jj < 4; ++jj) {
      f32x4 r;
#pragma unroll
      for (int i = 0; i < 4; ++i) r[i] = tile[dc * 16 + jj * 4 + i][q] * inv;
      *(f32x4*)&out[(size_t)(q0 + q) * HD + db * 64 + dc * 16 + jj * 4] = r;
    }
    __syncthreads();
  }
}

extern "C" void kernel_launch(void* const* d_in, const int* in_sizes, int n_in,
                              void* d_out, int out_size, void* d_ws, size_t ws_size,
                              hipStream_t stream) {
  const float* Q = (const float*)d_in[0];
  const float* K = (const float*)d_in[1];
  const float* V = (const float*)d_in[2];
  float* out = (float*)d_out;

  int ksplit = 8, kshift = 3;
  while (ksplit > 1) {
    size_t need = (size_t)ksplit * SEQ * HD * 4
                + (size_t)ksplit * SEQ * 4
                + (size_t)SEQ * HD * 2 * 2;
    if (need <= ws_size) break;
    ksplit >>= 1; kshift--;
  }

  char* ws = (char*)d_ws;
  float* OpartT = (float*)ws;
  float* Lpart = (float*)(ws + (size_t)ksplit * SEQ * HD * 4);
  bf16_t* Kb = (bf16_t*)(ws + (size_t)ksplit * SEQ * HD * 4 + (size_t)ksplit * SEQ * 4);
  bf16_t* VT = Kb + (size_t)SEQ * HD;

  const int nit = SEQ / (ksplit * BN);

  prep_kernel<<<768, 256, 0, stream>>>(K, V, Kb, VT);
  fattn_kernel<<<NQT * ksplit, THREADS, 0, stream>>>(Q, Kb, VT, OpartT, Lpart, kshift, nit);
  combine_kernel<<<SEQ / 64, 256, 0, stream>>>(OpartT, Lpart, out, ksplit);
}

// Round 9
// 122.450 us; speedup vs baseline: 1.0921x; 1.0052x over previous
//
#include <hip/hip_runtime.h>
#include <hip/hip_bf16.h>

#define SEQ 8192
#define HD 128
#define BM 256
#define BN 64
#define NQT (SEQ / BM)   // 32
#define THREADS 1024

typedef __bf16 bf16_t;
typedef __bf16 bf16x2 __attribute__((ext_vector_type(2)));
typedef __bf16 bf16x8 __attribute__((ext_vector_type(8)));
typedef float f32x4 __attribute__((ext_vector_type(4)));
typedef float f32x16 __attribute__((ext_vector_type(16)));
typedef unsigned int u32x4 __attribute__((ext_vector_type(4)));

#if __has_builtin(__builtin_amdgcn_exp2f)
__device__ inline float exp2_fast(float x) { return __builtin_amdgcn_exp2f(x); }
#else
__device__ inline float exp2_fast(float x) { return exp2f(x); }
#endif

// async global->LDS DMA, 16 B per lane; lds dest wave-uniform, HW adds lane*16
__device__ inline void load_lds16(const void* g, void* l) {
  __builtin_amdgcn_global_load_lds(
      (const __attribute__((address_space(1))) void*)g,
      (__attribute__((address_space(3))) void*)l, 16, 0, 0);
}

// ---------------- prep ----------------
// Kb blocked: [tile T][d-chunk c 0..15][key r 0..63][8]  = K[T*64+r][c*8+j]
// VT blocked: [tile T][key-chunk kc 0..7][d 0..127][8]   = V[T*64+kc*8+j][d]
__global__ __launch_bounds__(256) void prep_kernel(const float* __restrict__ K,
                                                   const float* __restrict__ V,
                                                   bf16_t* __restrict__ Kb,
                                                   bf16_t* __restrict__ VT) {
  const int b = (int)blockIdx.x;
  const int tid = (int)threadIdx.x;
  if (b < 256) {
    __shared__ float tile[64][65];
    const int T = b & 127;
    const int d0 = (b >> 7) * 64;
    const int s0 = T * 64;
    const int r = tid >> 2;
    const int c0 = (tid & 3) * 16;
#pragma unroll
    for (int j4 = 0; j4 < 4; ++j4) {
      float4 x = *(const float4*)&V[(size_t)(s0 + r) * HD + d0 + c0 + j4 * 4];
      tile[r][c0 + j4 * 4 + 0] = x.x;
      tile[r][c0 + j4 * 4 + 1] = x.y;
      tile[r][c0 + j4 * 4 + 2] = x.z;
      tile[r][c0 + j4 * 4 + 3] = x.w;
    }
    __syncthreads();
    const int d_l = tid & 63;
    const int kc0 = (tid >> 6) * 2;
#pragma unroll
    for (int k2 = 0; k2 < 2; ++k2) {
      const int kc = kc0 + k2;
      bf16x8 wv;
#pragma unroll
      for (int j = 0; j < 8; ++j) wv[j] = (bf16_t)tile[kc * 8 + j][d_l];
      *(bf16x8*)&VT[((size_t)(T * 8 + kc) * 128 + d0 + d_l) * 8] = wv;
    }
  } else {
    const int base = (b - 256) * 2048 + tid * 8;
    const int row = base >> 7;
    const int c = (base >> 3) & 15;
    const int T = row >> 6;
    const int r = row & 63;
    float4 a = *(const float4*)&K[base];
    float4 cc = *(const float4*)&K[base + 4];
    bf16x8 f;
    f[0] = (bf16_t)a.x; f[1] = (bf16_t)a.y; f[2] = (bf16_t)a.z; f[3] = (bf16_t)a.w;
    f[4] = (bf16_t)cc.x; f[5] = (bf16_t)cc.y; f[6] = (bf16_t)cc.z; f[7] = (bf16_t)cc.w;
    *(bf16x8*)&Kb[((size_t)(T * 16 + c) * 64 + r) * 8] = f;
  }
}

// ---------------- main flash-attention kernel ----------------
// BM=256, 1024 threads, 16 waves: qw = w&7 (32 q-rows), g = w>>3 (key-half
// for QK, d-half for PV). Software-pipelined P: iter `it` runs QK(it)+exp(it)
// (publish P(it) to pbuf) AND PV(it-1) — two independent streams, ONE barrier
// per iter. kt double-, vt triple-, pbuf double-buffered (144 KB LDS,
// 1 block/CU, 4 waves/SIMD).
__global__ __launch_bounds__(THREADS, 4) void fattn_kernel(
    const float* __restrict__ Q, const bf16_t* __restrict__ Kb,
    const bf16_t* __restrict__ VT, float* __restrict__ OpartT,
    float* __restrict__ Lpart, int kshift, int nit) {
  __shared__ __align__(16) bf16_t kt[2 * 8192];   // 32 KB [buf][d-chunk][key][8]
  __shared__ __align__(16) bf16_t vt[3 * 8192];   // 48 KB [buf][key-chunk][d][8]
  __shared__ __align__(16) char pbc[2 * 32768];   // 64 KB [buf][slot32][64][16]

  const int tid = (int)threadIdx.x;
  const int lane = tid & 63;
  const int w = tid >> 6;        // 0..15
  const int qw = w & 7;          // q-tile
  const int g = w >> 3;          // key-half (QK) / d-half (PV)
  const int h = lane >> 5;
  const int n32 = lane & 31;

  const int qt = (int)blockIdx.x >> kshift;
  const int sp = (int)blockIdx.x & ((1 << kshift) - 1);
  const int qbase = qt * BM;
  const int tile0 = sp * nit;

  const float SC2 = 0.08838834764831845f * 1.4426950408889634f; // (1/sqrt(128))*log2e

  // Q B-frags (n = n32 = q-row, k-dim = d), pre-scaled
  bf16x8 qf[8];
  {
    const float* qp = Q + (size_t)(qbase + qw * 32 + n32) * HD + h * 8;
#pragma unroll
    for (int kk = 0; kk < 8; ++kk) {
      float4 a = *(const float4*)(qp + kk * 16);
      float4 b = *(const float4*)(qp + kk * 16 + 4);
      bf16x8 f;
      f[0] = (bf16_t)(a.x * SC2); f[1] = (bf16_t)(a.y * SC2);
      f[2] = (bf16_t)(a.z * SC2); f[3] = (bf16_t)(a.w * SC2);
      f[4] = (bf16_t)(b.x * SC2); f[5] = (bf16_t)(b.y * SC2);
      f[6] = (bf16_t)(b.z * SC2); f[7] = (bf16_t)(b.w * SC2);
      qf[kk] = f;
    }
  }

  f32x16 o_acc[2];
#pragma unroll
  for (int i = 0; i < 2; ++i)
#pragma unroll
    for (int e = 0; e < 16; ++e) o_acc[i][e] = 0.f;
  float l_acc = 0.f;

  // DMA: per iter each wave moves 1 KB of kt (d-chunk w) + 1 KB of vt
  const bf16_t* ksrc = Kb + ((size_t)(tile0 * 16 + w) * 64 + lane) * 8;
  const bf16_t* vsrc = VT + ((size_t)(tile0 * 8 + (w >> 1)) * 128 + (w & 1) * 64 + lane) * 8;
  char* kdstb = (char*)kt + w * 1024;   // buf0 region
  char* vdstb = (char*)vt + w * 1024;

  // preload tile0 -> kt buf0, vt buf0
  load_lds16(ksrc, kdstb);
  load_lds16(vsrc, vdstb);
  ksrc += 8192;
  vsrc += 8192;
  __syncthreads();

  // per-lane LDS read bases
  const bf16_t* ktb = kt + (g * 32 + n32) * 8 + h * 512;       // + kt_ro + kk*1024
  const bf16_t* vtb = vt + (g * 64 + n32) * 8 + h * 1024;      // + v_pv + c*2048 + dt*256
  char* pbw = pbc + w * 2048 + lane * 16;                      // + p_wo + kk2*1024
  const char* pbr = pbc + qw * 2048 + lane * 16;               // + p_ro + (c>>1)*16384 + (c&1)*1024

  int kt_ro = 0;       // QK read buffer (elements)
  int ktd = 16384;     // kt DMA dest (bytes)
  int v_pv = 16384, v_nx = 0, v_fr = 8192;  // vt rotation (elements)
  int p_wo = 0;        // pbuf write offset (bytes); read = p_wo ^ 32768

  for (int it = 0; it <= nit; ++it) {
    if (it + 1 < nit) {
      load_lds16(ksrc, kdstb + ktd);
      load_lds16(vsrc, vdstb + 2 * v_fr);
      ksrc += 8192;
      vsrc += 8192;
    }

    if (it < nit) {
      // ---- S^T(key-half g) = K_g Q^T : 32 x 32, K-dim 128 ----
      const bf16_t* kr = ktb + kt_ro;
      f32x16 sacc;
#pragma unroll
      for (int e = 0; e < 16; ++e) sacc[e] = 0.f;
#pragma unroll
      for (int kk = 0; kk < 8; ++kk) {
        bf16x8 af = *(const bf16x8*)(kr + kk * 1024);
        sacc = __builtin_amdgcn_mfma_f32_32x32x16_bf16(af, qf[kk], sacc, 0, 0, 0);
      }
      // ---- exp -> pack -> half-wave exchange -> publish P(it) ----
      // sacc[r] = S^T[key = g*32 + (r&3)+8*(r>>2)+4h][q = n32]
#pragma unroll
      for (int kk2 = 0; kk2 < 2; ++kk2) {
        float pf[8];
#pragma unroll
        for (int j = 0; j < 8; ++j) pf[j] = exp2_fast(sacc[8 * kk2 + j]);
#pragma unroll
        for (int j = 0; j < 8; ++j) l_acc += pf[j];
        bf16x2 p0, p1, p2, p3;
        p0[0] = (bf16_t)pf[0]; p0[1] = (bf16_t)pf[1];
        p1[0] = (bf16_t)pf[2]; p1[1] = (bf16_t)pf[3];
        p2[0] = (bf16_t)pf[4]; p2[1] = (bf16_t)pf[5];
        p3[0] = (bf16_t)pf[6]; p3[1] = (bf16_t)pf[7];
        const unsigned int sA = __builtin_bit_cast(unsigned int, p0);
        const unsigned int sB = __builtin_bit_cast(unsigned int, p1);
        const unsigned int sC = __builtin_bit_cast(unsigned int, p2);
        const unsigned int sD = __builtin_bit_cast(unsigned int, p3);
        unsigned int s0 = h ? sA : sC, s1 = h ? sB : sD;
        unsigned int r0 = __shfl_xor(s0, 32);
        unsigned int r1 = __shfl_xor(s1, 32);
        unsigned int o0 = h ? sC : sA, o1 = h ? sD : sB;
        u32x4 fv;
        fv[0] = h ? r0 : o0; fv[1] = h ? r1 : o1;
        fv[2] = h ? o0 : r0; fv[3] = h ? o1 : r1;
        *(u32x4*)(pbw + p_wo + kk2 * 1024) = fv;
      }
    }

    if (it > 0) {
      // ---- O^T(d-half g) += V^T(it-1) P(it-1) over all 64 keys ----
      const bf16_t* vr = vtb + v_pv;
      const char* pr = pbr + (p_wo ^ 32768);
#pragma unroll
      for (int c = 0; c < 4; ++c) {
        bf16x8 pb = *(const bf16x8*)(pr + (c >> 1) * 16384 + (c & 1) * 1024);
#pragma unroll
        for (int dt = 0; dt < 2; ++dt) {
          bf16x8 av = *(const bf16x8*)(vr + c * 2048 + dt * 256);
          o_acc[dt] = __builtin_amdgcn_mfma_f32_32x32x16_bf16(av, pb, o_acc[dt], 0, 0, 0);
        }
      }
    }

    if (it < nit) __syncthreads();   // drains DMA + LDS; publishes P(it)

    // rotate buffers
    kt_ro ^= 8192;
    ktd ^= 16384;
    int tswp = v_pv; v_pv = v_nx; v_nx = v_fr; v_fr = tswp;
    p_wo ^= 32768;
  }

  // ---- epilogue: each wave owns a distinct (q-tile, d-half) block of O^T ----
  {
    float* op = OpartT + (size_t)sp * HD * SEQ + qbase + qw * 32 + n32;
#pragma unroll
    for (int dt = 0; dt < 2; ++dt)
#pragma unroll
      for (int reg = 0; reg < 16; ++reg) {
        const int d = g * 64 + dt * 32 + (reg & 3) + 8 * (reg >> 2) + 4 * h;
        op[(size_t)d * SEQ] = o_acc[dt][reg];
      }
    float l = l_acc + __shfl_xor(l_acc, 32);
    __syncthreads();                      // pbuf reads done; reuse as lfb
    float* lfb = (float*)pbc;
    if (lane < 32) lfb[g * 256 + qw * 32 + n32] = l;
    __syncthreads();
    if (g == 0 && lane < 32)
      Lpart[(size_t)sp * SEQ + qbase + qw * 32 + n32] =
          l + lfb[256 + qw * 32 + n32];
  }
}

// ---------------- combine: out[q][d] = (sum_s OpartT[s][d][q]) / sum_s l_s[q] ----
__global__ __launch_bounds__(256) void combine_kernel(const float* __restrict__ OpartT,
                                                      const float* __restrict__ Lpart,
                                                      float* __restrict__ out, int ksplit) {
  __shared__ float tile[64][68];
  __shared__ float lbuf[64];
  const int tid = (int)threadIdx.x;
  const int q0 = (int)blockIdx.x * 64;
  if (tid < 64) {
    float s = 0.f;
    for (int sp = 0; sp < ksplit; ++sp) s += Lpart[(size_t)sp * SEQ + q0 + tid];
    lbuf[tid] = 1.0f / s;
  }
  __syncthreads();
  const int dd = tid >> 2, qc = tid & 3;   // phase A mapping
  const int q = tid >> 2, dc = tid & 3;    // phase B mapping
  for (int db = 0; db < 2; ++db) {
    f32x4 acc[4];
#pragma unroll
    for (int jj = 0; jj < 4; ++jj)
#pragma unroll
      for (int e = 0; e < 4; ++e) acc[jj][e] = 0.f;
    for (int sp = 0; sp < ksplit; ++sp) {
      const float* src = OpartT + ((size_t)sp * HD + db * 64 + dd) * SEQ + q0 + qc * 16;
#pragma unroll
      for (int jj = 0; jj < 4; ++jj) {
        f32x4 v = *(const f32x4*)(src + jj * 4);
#pragma unroll
        for (int e = 0; e < 4; ++e) acc[jj][e] += v[e];
      }
    }
#pragma unroll
    for (int jj = 0; jj < 4; ++jj) *(f32x4*)&tile[dd][qc * 16 + jj * 4] = acc[jj];
    __syncthreads();
    const float inv = lbuf[q];
#pragma unroll
    for (int jj = 0; jj < 4; ++jj) {
      f32x4 r;
#pragma unroll
      for (int i = 0; i < 4; ++i) r[i] = tile[dc * 16 + jj * 4 + i][q] * inv;
      *(f32x4*)&out[(size_t)(q0 + q) * HD + db * 64 + dc * 16 + jj * 4] = r;
    }
    __syncthreads();
  }
}

extern "C" void kernel_launch(void* const* d_in, const int* in_sizes, int n_in,
                              void* d_out, int out_size, void* d_ws, size_t ws_size,
                              hipStream_t stream) {
  const float* Q = (const float*)d_in[0];
  const float* K = (const float*)d_in[1];
  const float* V = (const float*)d_in[2];
  float* out = (float*)d_out;

  int ksplit = 8, kshift = 3;
  while (ksplit > 1) {
    size_t need = (size_t)ksplit * SEQ * HD * 4
                + (size_t)ksplit * SEQ * 4
                + (size_t)SEQ * HD * 2 * 2;
    if (need <= ws_size) break;
    ksplit >>= 1; kshift--;
  }

  char* ws = (char*)d_ws;
  float* OpartT = (float*)ws;
  float* Lpart = (float*)(ws + (size_t)ksplit * SEQ * HD * 4);
  bf16_t* Kb = (bf16_t*)(ws + (size_t)ksplit * SEQ * HD * 4 + (size_t)ksplit * SEQ * 4);
  bf16_t* VT = Kb + (size_t)SEQ * HD;

  const int nit = SEQ / (ksplit * BN);

  prep_kernel<<<768, 256, 0, stream>>>(K, V, Kb, VT);
  fattn_kernel<<<NQT * ksplit, THREADS, 0, stream>>>(Q, Kb, VT, OpartT, Lpart, kshift, nit);
  combine_kernel<<<SEQ / 64, 256, 0, stream>>>(OpartT, Lpart, out, ksplit);
}